// Round 3
// baseline (1318.883 us; speedup 1.0000x reference)
//
#include <hip/hip_runtime.h>
#include <math.h>

// Problem constants (from reference)
#define TT 2048
#define BB 512
#define II 11
#define HH 33
#define NL 3
#define OO 18
#define FSLOT 40          // fp32 slots per LDS vector (160 B, 16B-aligned)

typedef float f2 __attribute__((ext_vector_type(2)));
typedef float f4 __attribute__((ext_vector_type(4)));

// fast sigmoid / tanh via v_exp_f32 + v_rcp_f32 (saturate correctly at +-inf)
__device__ __forceinline__ float sigm_f(float x) {
    float e = __expf(-x);
    return __builtin_amdgcn_rcpf(1.0f + e);
}
__device__ __forceinline__ float tanh_f(float x) {
    float e = __expf(2.0f * x);
    return 1.0f - 2.0f * __builtin_amdgcn_rcpf(e + 1.0f);
}

// lane<->lane^1 exchange via DPP quad_perm [1,0,3,2] (pure VALU, no LDS)
__device__ __forceinline__ float dppx1(float v) {
    return __int_as_float(__builtin_amdgcn_update_dpp(
        0, __float_as_int(v), 0xB1 /*quad_perm 1,0,3,2*/, 0xF, 0xF, true));
}

// Layer-pipelined LSTM, TWO LANES PER UNIT (K-split + DPP pair reduce), fused MLP.
// MAC engine: plain scalar v_fmac_f32 (full-rate: 1 wave-inst / 2 cy -- this is
// what the 157.3 TF fp32 vector spec assumes, and unlike VOP3P dot2/pk_fma it
// can source the unified VGPR/AGPR file directly, so no per-MAC accvgpr copies.
// R0/R1 fdot2 measured ~8cy effective; R2 pk_fma+asm ~= copies galore).
// grid = 512 blocks (one batch element each), block = 256 threads (4 waves)
//   -> 2 blocks/CU, 2 waves/SIMD.
// tid < 198: unit u = tid>>1, half hf = tid&1. hf=0 owns k 0..15, hf=1 owns
//   k 16..33 of ALL 4 gate rows (input side + own-h side) => 144 scalar FMAs
//   per lane as 4 independent 36-deep fp32 chains (2cy issue, 4-way ILP).
//   Pair combine: 4 DPP(lane^1) adds; transcendentals split across the pair
//   (hf0: i,f; hf1: g,o); only hf0's (c,h) are consumed, so no gate
//   re-selection -- hf1's c evolves as bounded garbage (no NaN, see note).
// tid 200..210: x prefetchers (11 features), 2-deep software pipeline.
// LDS: ping-pong fp32 buf[2][4][FSLOT]; one barrier per superstep; peeled
// steady state with compile-time ping-pong.
__global__ __launch_bounds__(256, 2) void lstm_pipeline_kernel(
    const float* __restrict__ x,
    const float* __restrict__ Wih0, const float* __restrict__ Whh0,
    const float* __restrict__ bih0, const float* __restrict__ bhh0,
    const float* __restrict__ Wih1, const float* __restrict__ Whh1,
    const float* __restrict__ bih1, const float* __restrict__ bhh1,
    const float* __restrict__ Wih2, const float* __restrict__ Whh2,
    const float* __restrict__ bih2, const float* __restrict__ bhh2,
    const float* __restrict__ W1, const float* __restrict__ b1,
    const float* __restrict__ W2, const float* __restrict__ b2,
    float* __restrict__ hidden_out,   // [3, 512, 33]
    float* __restrict__ outp)         // [3, 512, 18]
{
    __shared__ __align__(16) float buf[2][NL + 1][FSLOT];
    __shared__ float hfin[NL][HH + 1];   // final h per layer (fp32, fused MLP)
    __shared__ float h1s[NL][4 * OO];    // MLP hidden

    const int tid = threadIdx.x;
    const int bg  = blockIdx.x;

    for (int i = tid; i < 2 * (NL + 1) * FSLOT; i += 256)
        ((float*)buf)[i] = 0.0f;

    const bool comp = (tid < 2 * 99);
    const int  u    = tid >> 1;                 // unit 0..98
    const int  hf   = tid & 1;                  // K-half: 0 -> k0..15, 1 -> k16..33
    const int  l    = (u < 33) ? 0 : (u < 66) ? 1 : 2;
    const int  j    = u - 33 * l;
    const int  koff = hf ? 16 : 0;

    const int  pi   = tid - 200;
    const bool pref = (pi >= 0) && (pi < II);
    const int  pic  = pref ? pi : 0;
    const float* xrow = x + (size_t)bg * TT * II + pic;

    // ---- per-lane weights: 4 gates x (input + own) x 18 k-slots (fp32) ----
    // hf0 uses slots 0..15 (16,17 zeroed); hf1 uses 0..17 = k 16..33 (33 OOR->0)
    float wI[4][18], wH[4][18];
    #pragma unroll
    for (int g = 0; g < 4; ++g)
        #pragma unroll
        for (int r = 0; r < 18; ++r) { wI[g][r] = 0.0f; wH[g][r] = 0.0f; }
    float b0 = 0.0f, b1v = 0.0f, b2v = 0.0f, b3v = 0.0f;   // bias on hf=0 only

    if (comp) {
        if (!hf) {
            const float* bip = (l == 0) ? bih0 : (l == 1) ? bih1 : bih2;
            const float* bhp = (l == 0) ? bhh0 : (l == 1) ? bhh1 : bhh2;
            b0  = bip[0 * HH + j] + bhp[0 * HH + j];
            b1v = bip[1 * HH + j] + bhp[1 * HH + j];
            b2v = bip[2 * HH + j] + bhp[2 * HH + j];
            b3v = bip[3 * HH + j] + bhp[3 * HH + j];
        }
        const float* Wi = (l == 0) ? Wih0 : (l == 1) ? Wih1 : Wih2;
        const float* Wh = (l == 0) ? Whh0 : (l == 1) ? Whh1 : Whh2;
        const int kin = (l == 0) ? II : HH;
        #pragma unroll
        for (int g = 0; g < 4; ++g) {
            const float* rw = Wi + (g * HH + j) * kin;
            const float* rh = Wh + (g * HH + j) * HH;
            #pragma unroll
            for (int r = 0; r < 18; ++r) {
                const int  k    = koff + r;
                const bool own  = hf ? true : (r < 16);   // hf0 owns only k0..15
                wI[g][r] = (own && k < kin) ? rw[k] : 0.0f;
                wH[g][r] = (own && k < HH)  ? rh[k] : 0.0f;
            }
        }
    }

    // lane-constant unified nonlinearity coefs: xg = AX + BX * rcp(exp(kX*a)+1)
    //   hf=0: sigm(s0) -> kX=-1, AX=0, BX=+1      (gate i)
    //   hf=1: tanh(s2) -> kX=+2, AX=1, BX=-2      (gate g)
    const float kX = hf ? 2.0f : -1.0f;
    const float AX = hf ? 1.0f : 0.0f;
    const float BX = hf ? -2.0f : 1.0f;

    __syncthreads();
    float v_next = 0.0f, v_next2 = 0.0f;
    if (pref) {
        buf[0][0][pi] = xrow[0];
        v_next  = xrow[II];
        v_next2 = xrow[2 * II];
    }
    __syncthreads();

    float c = 0.0f;

    // hoisted ping-pong pointers (compile-time selected in peeled steps)
    const float* rin[2]  = { &buf[0][l][0],     &buf[1][l][0] };      // input vec
    const float* rown[2] = { &buf[0][l + 1][0], &buf[1][l + 1][0] };  // own-h vec
    float*       wrp[2]  = { &buf[0][l + 1][j], &buf[1][l + 1][j] };
    float*       pxp[2]  = { &buf[0][0][pic],   &buf[1][0][pic] };

    // one superstep; all bool/int args are compile-time constants at call sites
    auto step = [&](int s, int rp, bool check, bool out, bool xload, bool xstore)
        __attribute__((always_inline)) {
        const int wp = rp ^ 1;
        if (pref) {
            if (xstore) *pxp[wp] = v_next;
            v_next = v_next2;
            if (xload) v_next2 = xrow[(size_t)(s + 3) * II];
        }
        const bool active = check ? (comp && (s >= l) && (s - l < TT)) : comp;
        if (active) {
            const float* ri = rin[rp] + koff;
            const float* ro = rown[rp] + koff;
            // 18 floats per side: 4 x b128 + 1 x b64, 16B/8B aligned for both
            // halves (koff in {0,16} floats). Even/odd lanes read 2 distinct
            // addresses -> broadcast, conflict-free.
            float vi[18], vo[18];
            #pragma unroll
            for (int q = 0; q < 4; ++q) {
                const f4 a = *(const f4*)(ri + 4 * q);
                const f4 b = *(const f4*)(ro + 4 * q);
                vi[4 * q + 0] = a.x; vi[4 * q + 1] = a.y; vi[4 * q + 2] = a.z; vi[4 * q + 3] = a.w;
                vo[4 * q + 0] = b.x; vo[4 * q + 1] = b.y; vo[4 * q + 2] = b.z; vo[4 * q + 3] = b.w;
            }
            { const f2 a = *(const f2*)(ri + 16); vi[16] = a.x; vi[17] = a.y;
              const f2 b = *(const f2*)(ro + 16); vo[16] = b.x; vo[17] = b.y; }

            // ---- 144 scalar v_fmac_f32 as 4 independent 36-deep chains ----
            float s0 = b0, s1 = b1v, s2 = b2v, s3 = b3v;
            #pragma unroll
            for (int r = 0; r < 18; ++r) {
                s0 = __builtin_fmaf(wI[0][r], vi[r], s0);
                s1 = __builtin_fmaf(wI[1][r], vi[r], s1);
                s2 = __builtin_fmaf(wI[2][r], vi[r], s2);
                s3 = __builtin_fmaf(wI[3][r], vi[r], s3);
            }
            #pragma unroll
            for (int r = 0; r < 18; ++r) {
                s0 = __builtin_fmaf(wH[0][r], vo[r], s0);
                s1 = __builtin_fmaf(wH[1][r], vo[r], s1);
                s2 = __builtin_fmaf(wH[2][r], vo[r], s2);
                s3 = __builtin_fmaf(wH[3][r], vo[r], s3);
            }

            // ---- pair reduce: full gate pre-activations on BOTH lanes ----
            s0 += dppx1(s0); s1 += dppx1(s1);
            s2 += dppx1(s2); s3 += dppx1(s3);

            // ---- split transcendentals: hf0 computes i,f; hf1 computes g,o ----
            const float aXv = hf ? s2 : s0;
            const float eX  = __expf(kX * aXv);
            const float rX  = __builtin_amdgcn_rcpf(1.0f + eX);
            const float xg  = __builtin_fmaf(BX, rX, AX);   // hf0: i   hf1: g
            const float yg  = sigm_f(hf ? s3 : s1);         // hf0: f   hf1: o

            // prod = i*g identically on both lanes; f/o only correct on hf0
            // (hf1's c/h are never consumed: c stays bounded, no NaN -- o<1
            //  geometric decay, tanh_f saturates cleanly at +-inf).
            const float prod = xg * dppx1(xg);
            const float yp   = dppx1(yg);                   // hf0: o
            c = __builtin_fmaf(yg, c, prod);                // hf0: f*c + i*g
            const float hnew = yp * tanh_f(c);              // hf0: o*tanh(c)

            if (!hf) {
                *wrp[wp] = hnew;
                if (out && (s - l == TT - 1)) {
                    hidden_out[((size_t)l * BB + bg) * HH + j] = hnew;
                    hfin[l][j] = hnew;
                }
            }
        }
        __syncthreads();
    };

    // prologue (pipeline fill, masked)
    step(0, 0, true, false, true, true);
    step(1, 1, true, false, true, true);
    // steady state: s = 2..2043 as constant-rp pairs (no checks, no outputs)
    for (int s = 2; s < TT - 4; s += 2) {
        step(s,     0, false, false, true, true);
        step(s + 1, 1, false, false, true, true);
    }
    // tail of steady state + epilogue (drain + final-h outputs)
    step(TT - 4, 0, false, false, true,  true);    // s=2044 (last x load)
    step(TT - 3, 1, false, false, false, true);    // s=2045
    step(TT - 2, 0, false, false, false, true);    // s=2046 (stores x[2047])
    step(TT - 1, 1, false, true,  false, false);   // s=2047: l0 writes hT
    step(TT,     0, true,  true,  false, false);   // s=2048: l1 writes hT
    step(TT + 1, 1, true,  true,  false, false);   // s=2049: l2 writes hT

    // ---- fused MLP head (hfin visible after the last step's barrier) ----
    // h1 = gelu_exact(hfin @ W1^T + b1) [3,72]; out = h1 @ W2^T + b2 [3,18]
    if (tid < 4 * OO) {                   // 72 threads x 3 layers
        #pragma unroll
        for (int ml = 0; ml < NL; ++ml) {
            float a = b1[tid];
            #pragma unroll
            for (int k = 0; k < HH; ++k) a += hfin[ml][k] * W1[tid * HH + k];
            h1s[ml][tid] = 0.5f * a * (1.0f + erff(a * 0.70710678118654752f));
        }
    }
    __syncthreads();
    if (tid < NL * OO) {                  // 54 threads
        const int ol = tid / OO, o = tid % OO;
        float a = b2[o];
        #pragma unroll
        for (int m = 0; m < 4 * OO; ++m) a += h1s[ol][m] * W2[o * (4 * OO) + m];
        outp[((size_t)ol * BB + bg) * OO + o] = a;
    }
}

extern "C" void kernel_launch(void* const* d_in, const int* in_sizes, int n_in,
                              void* d_out, int out_size, void* d_ws, size_t ws_size,
                              hipStream_t stream) {
    const float* x    = (const float*)d_in[0];
    const float* Wih0 = (const float*)d_in[1];
    const float* Whh0 = (const float*)d_in[2];
    const float* bih0 = (const float*)d_in[3];
    const float* bhh0 = (const float*)d_in[4];
    const float* Wih1 = (const float*)d_in[5];
    const float* Whh1 = (const float*)d_in[6];
    const float* bih1 = (const float*)d_in[7];
    const float* bhh1 = (const float*)d_in[8];
    const float* Wih2 = (const float*)d_in[9];
    const float* Whh2 = (const float*)d_in[10];
    const float* bih2 = (const float*)d_in[11];
    const float* bhh2 = (const float*)d_in[12];
    const float* W1   = (const float*)d_in[13];
    const float* b1   = (const float*)d_in[14];
    const float* W2   = (const float*)d_in[15];
    const float* b2   = (const float*)d_in[16];

    float* out    = (float*)d_out;                 // [3,512,18] = 27648 floats
    float* hidden = out + NL * BB * OO;            // [3,512,33] = 50688 floats

    lstm_pipeline_kernel<<<BB, 256, 0, stream>>>(
        x, Wih0, Whh0, bih0, bhh0, Wih1, Whh1, bih1, bhh1,
        Wih2, Whh2, bih2, bhh2, W1, b1, W2, b2, hidden, out);
}

// Round 4
// 1052.354 us; speedup vs baseline: 1.2533x; 1.2533x over previous
//
#include <hip/hip_runtime.h>
#include <math.h>

// Problem constants (from reference)
#define TT 2048
#define BB 512
#define II 11
#define HH 33
#define NL 3
#define OO 18
#define HSLOT 48          // halves per LDS vector slot (96 B, 16B-aligned slots)

typedef _Float16 h2 __attribute__((ext_vector_type(2)));
typedef _Float16 h8 __attribute__((ext_vector_type(8)));   // 16 B -> ds_read_b128

// fast sigmoid / tanh via v_exp_f32 + v_rcp_f32 (saturate correctly at +-inf)
__device__ __forceinline__ float sigm_f(float x) {
    float e = __expf(-x);
    return __builtin_amdgcn_rcpf(1.0f + e);
}
__device__ __forceinline__ float tanh_f(float x) {
    float e = __expf(2.0f * x);
    return 1.0f - 2.0f * __builtin_amdgcn_rcpf(e + 1.0f);
}

// guarded fp32->fp16 row-slice loads (zero-pad past rem)
__device__ __forceinline__ h8 gldh8(const float* p, int k0, int rem) {
    h8 v;
    #pragma unroll
    for (int i = 0; i < 8; ++i) v[i] = (_Float16)((k0 + i < rem) ? p[k0 + i] : 0.0f);
    return v;
}
__device__ __forceinline__ h2 gldh2(const float* p, int k0, int rem) {
    h2 v;
    v.x = (_Float16)((k0 + 0 < rem) ? p[k0 + 0] : 0.0f);
    v.y = (_Float16)((k0 + 1 < rem) ? p[k0 + 1] : 0.0f);
    return v;
}

// v_dot2_f32_f16: 2 MACs/op, fp32 accumulate
#define FD(a, p, q) a = __builtin_amdgcn_fdot2((p), (q), a, false)
// one 2-half slice fed to all 8 chains (4 input-side + 4 own-h-side).
// Same-chain reuse distance = 8 insts = 16 cy > fdot2 dep latency ->
// the whole MAC section is ISSUE-bound (R0's two sequential 34-deep
// 2-chain phases were LATENCY-bound, ~2x this cost).
#define DUO(vi_, vo_, SEL) do { \
    FD(a0i, (vi_).SEL, (xw0).SEL); FD(a1i, (vi_).SEL, (xw1).SEL); \
    FD(a2i, (vi_).SEL, (xw2).SEL); FD(a3i, (vi_).SEL, (xw3).SEL); \
    FD(a0h, (vo_).SEL, (hw0).SEL); FD(a1h, (vo_).SEL, (hw1).SEL); \
    FD(a2h, (vo_).SEL, (hw2).SEL); FD(a3h, (vo_).SEL, (hw3).SEL); } while (0)
#define DUOQ(vi_, vo_, xq0, xq1, xq2, xq3, hq0, hq1, hq2, hq3) do { \
    const h8 xw0 = (xq0), xw1 = (xq1), xw2 = (xq2), xw3 = (xq3); \
    const h8 hw0 = (hq0), hw1 = (hq1), hw2 = (hq2), hw3 = (hq3); \
    DUO(vi_, vo_, s01); DUO(vi_, vo_, s23); \
    DUO(vi_, vo_, s45); DUO(vi_, vo_, s67); } while (0)

// Layer-pipelined LSTM, ONE LANE PER UNIT (no cross-lane ops), fused MLP head.
// grid = 512 blocks (one batch element each), block = 128 threads (2 waves)
//   -> 1 wave/SIMD: deliberately LOW occupancy. Each block is a 2050-step
//   serial recurrence; wall time = per-step critical path, and co-resident
//   waves only add issue contention (R1/R3 measured +4%/+25% worse at
//   2 waves/SIMD). VALUBusy in the CSV is ~2x-inflated (gfx94x SIMD-16
//   formula on SIMD-32 hardware): real VALU busy at R0 was ~30%.
//   tid < 99 : unit u = tid, l = u/33, j = u%33. The lane holds ALL weights of
//   its unit (4 gate rows x (input 34 + own-h 34) halves, packed fp16), reads
//   the layer-input vector (slot l) and own-h vector (slot l+1) from LDS
//   (broadcast reads), runs 136 fdot2 as 8 INDEPENDENT 17-deep chains
//   (issue-bound single phase), then the full gate nonlinearity + c/h locally.
//   tid 99..109 : x prefetchers (11 features), 2-deep software pipeline.
// Epilogue: final h of each layer staged in LDS (fp32), then the tiny MLP head
// (gelu(h@W1^T+b1)@W2^T+b2) runs in-block -- no second dispatch.
// LDS: ping-pong buf[2][4][HSLOT] halves; one barrier per superstep; peeled
// steady state with compile-time ping-pong.
__global__ __launch_bounds__(128, 1) void lstm_pipeline_kernel(
    const float* __restrict__ x,
    const float* __restrict__ Wih0, const float* __restrict__ Whh0,
    const float* __restrict__ bih0, const float* __restrict__ bhh0,
    const float* __restrict__ Wih1, const float* __restrict__ Whh1,
    const float* __restrict__ bih1, const float* __restrict__ bhh1,
    const float* __restrict__ Wih2, const float* __restrict__ Whh2,
    const float* __restrict__ bih2, const float* __restrict__ bhh2,
    const float* __restrict__ W1, const float* __restrict__ b1,
    const float* __restrict__ W2, const float* __restrict__ b2,
    float* __restrict__ hidden_out,   // [3, 512, 33]
    float* __restrict__ outp)         // [3, 512, 18]
{
    __shared__ __align__(16) _Float16 buf[2][NL + 1][HSLOT];
    __shared__ float hfin[NL][HH + 1];   // final h per layer (fp32, fused MLP)
    __shared__ float h1s[NL][4 * OO];    // MLP hidden

    const int tid = threadIdx.x;
    const int bg  = blockIdx.x;

    for (int i = tid; i < 2 * (NL + 1) * HSLOT; i += 128)
        ((_Float16*)buf)[i] = (_Float16)0.0f;

    const bool comp = (tid < 99);
    const int  u    = tid;
    const int  l    = (u < 33) ? 0 : (u < 66) ? 1 : 2;
    const int  j    = u - 33 * l;

    const int  pi   = tid - 99;
    const bool pref = (pi >= 0) && (pi < II);
    const float* xrow = x + (size_t)bg * TT * II + (pref ? pi : 0);

    // ---- per-lane weights: 4 gates x (input 34 + own 34) halves, named regs ----
    h8 z8 = {0,0,0,0,0,0,0,0};
    h2 z2 = {(_Float16)0.0f, (_Float16)0.0f};
    h8 x00=z8,x01=z8,x02=z8,x03=z8; h2 x0t=z2;   // gate i, input side (W_ih row)
    h8 x10=z8,x11=z8,x12=z8,x13=z8; h2 x1t=z2;   // gate f
    h8 x20=z8,x21=z8,x22=z8,x23=z8; h2 x2t=z2;   // gate g
    h8 x30=z8,x31=z8,x32=z8,x33=z8; h2 x3t=z2;   // gate o
    h8 h00=z8,h01=z8,h02=z8,h03=z8; h2 h0t=z2;   // gate i, own-h side (W_hh row)
    h8 h10=z8,h11=z8,h12=z8,h13=z8; h2 h1t=z2;
    h8 h20=z8,h21=z8,h22=z8,h23=z8; h2 h2t=z2;
    h8 h30=z8,h31=z8,h32=z8,h33=z8; h2 h3t=z2;
    float b0 = 0.0f, b1v = 0.0f, b2v = 0.0f, b3v = 0.0f;

    if (comp) {
        const float* bip = (l == 0) ? bih0 : (l == 1) ? bih1 : bih2;
        const float* bhp = (l == 0) ? bhh0 : (l == 1) ? bhh1 : bhh2;
        b0  = bip[0 * HH + j] + bhp[0 * HH + j];
        b1v = bip[1 * HH + j] + bhp[1 * HH + j];
        b2v = bip[2 * HH + j] + bhp[2 * HH + j];
        b3v = bip[3 * HH + j] + bhp[3 * HH + j];

        const float* Wi = (l == 0) ? Wih0 : (l == 1) ? Wih1 : Wih2;
        const float* Wh = (l == 0) ? Whh0 : (l == 1) ? Whh1 : Whh2;
        const int kin = (l == 0) ? II : HH;
        const float* r0 = Wi + (0 * HH + j) * kin;
        const float* r1 = Wi + (1 * HH + j) * kin;
        const float* r2 = Wi + (2 * HH + j) * kin;
        const float* r3 = Wi + (3 * HH + j) * kin;
        x00=gldh8(r0,0,kin); x01=gldh8(r0,8,kin); x02=gldh8(r0,16,kin); x03=gldh8(r0,24,kin); x0t=gldh2(r0,32,kin);
        x10=gldh8(r1,0,kin); x11=gldh8(r1,8,kin); x12=gldh8(r1,16,kin); x13=gldh8(r1,24,kin); x1t=gldh2(r1,32,kin);
        x20=gldh8(r2,0,kin); x21=gldh8(r2,8,kin); x22=gldh8(r2,16,kin); x23=gldh8(r2,24,kin); x2t=gldh2(r2,32,kin);
        x30=gldh8(r3,0,kin); x31=gldh8(r3,8,kin); x32=gldh8(r3,16,kin); x33=gldh8(r3,24,kin); x3t=gldh2(r3,32,kin);
        const float* s0 = Wh + (0 * HH + j) * HH;
        const float* s1 = Wh + (1 * HH + j) * HH;
        const float* s2 = Wh + (2 * HH + j) * HH;
        const float* s3 = Wh + (3 * HH + j) * HH;
        h00=gldh8(s0,0,HH); h01=gldh8(s0,8,HH); h02=gldh8(s0,16,HH); h03=gldh8(s0,24,HH); h0t=gldh2(s0,32,HH);
        h10=gldh8(s1,0,HH); h11=gldh8(s1,8,HH); h12=gldh8(s1,16,HH); h13=gldh8(s1,24,HH); h1t=gldh2(s1,32,HH);
        h20=gldh8(s2,0,HH); h21=gldh8(s2,8,HH); h22=gldh8(s2,16,HH); h23=gldh8(s2,24,HH); h2t=gldh2(s2,32,HH);
        h30=gldh8(s3,0,HH); h31=gldh8(s3,8,HH); h32=gldh8(s3,16,HH); h33=gldh8(s3,24,HH); h3t=gldh2(s3,32,HH);
    }

    __syncthreads();
    float v_next = 0.0f, v_next2 = 0.0f;
    if (pref) {
        buf[0][0][pi] = (_Float16)xrow[0];
        v_next  = xrow[II];
        v_next2 = xrow[2 * II];
    }
    __syncthreads();

    float c = 0.0f;

    // hoisted ping-pong pointers (compile-time selected in peeled steps)
    const _Float16* rin[2]  = { &buf[0][l][0],     &buf[1][l][0] };      // input vec
    const _Float16* rown[2] = { &buf[0][l + 1][0], &buf[1][l + 1][0] };  // own-h vec
    _Float16*       wrp[2]  = { &buf[0][l + 1][j], &buf[1][l + 1][j] };
    _Float16*       pxp[2]  = { &buf[0][0][pi],    &buf[1][0][pi] };

    // one superstep; all bool/int args are compile-time constants at call sites
    auto step = [&](int s, int rp, bool check, bool out, bool xload, bool xstore)
        __attribute__((always_inline)) {
        const int wp = rp ^ 1;
        if (pref) {
            if (xstore) *pxp[wp] = (_Float16)v_next;
            v_next = v_next2;
            if (xload) v_next2 = xrow[(size_t)(s + 3) * II];
        }
        const bool active = check ? (comp && (s >= l) && (s - l < TT)) : comp;
        if (active) {
            const h8* VI = (const h8*)rin[rp];
            const h8 vi0 = VI[0], vi1 = VI[1], vi2 = VI[2], vi3 = VI[3];
            const h2 vit = *(const h2*)(rin[rp] + 32);
            const h8* VO = (const h8*)rown[rp];
            const h8 vo0 = VO[0], vo1 = VO[1], vo2 = VO[2], vo3 = VO[3];
            const h2 vot = *(const h2*)(rown[rp] + 32);

            // ---- single MAC phase: 8 independent 17-deep fdot2 chains ----
            // (input-side chains carry the bias; own-h chains start at 0;
            //  one add per gate merges them at the end)
            float a0i = b0, a1i = b1v, a2i = b2v, a3i = b3v;
            float a0h = 0.0f, a1h = 0.0f, a2h = 0.0f, a3h = 0.0f;
            DUOQ(vi0, vo0, x00, x10, x20, x30, h00, h10, h20, h30);
            DUOQ(vi1, vo1, x01, x11, x21, x31, h01, h11, h21, h31);
            DUOQ(vi2, vo2, x02, x12, x22, x32, h02, h12, h22, h32);
            DUOQ(vi3, vo3, x03, x13, x23, x33, h03, h13, h23, h33);
            FD(a0i, vit, x0t); FD(a1i, vit, x1t);
            FD(a2i, vit, x2t); FD(a3i, vit, x3t);
            FD(a0h, vot, h0t); FD(a1h, vot, h1t);
            FD(a2h, vot, h2t); FD(a3h, vot, h3t);

            const float s0 = a0i + a0h;   // gate i
            const float s1 = a1i + a1h;   // gate f
            const float s2 = a2i + a2h;   // gate g
            const float s3 = a3i + a3h;   // gate o

            // ---- tail: 4 independent trans chains, then the c/h chain ----
            const float ig = sigm_f(s0);
            const float fg = sigm_f(s1);
            const float gg = tanh_f(s2);
            const float og = sigm_f(s3);
            c = __builtin_fmaf(fg, c, ig * gg);
            const float hnew = og * tanh_f(c);

            *wrp[wp] = (_Float16)hnew;
            if (out && (s - l == TT - 1)) {
                hidden_out[((size_t)l * BB + bg) * HH + j] = hnew;
                hfin[l][j] = hnew;
            }
        }
        __syncthreads();
    };

    // prologue (pipeline fill, masked)
    step(0, 0, true, false, true, true);
    step(1, 1, true, false, true, true);
    // steady state: s = 2..2043 as constant-rp pairs (no checks, no outputs)
    for (int s = 2; s < TT - 4; s += 2) {
        step(s,     0, false, false, true, true);
        step(s + 1, 1, false, false, true, true);
    }
    // tail of steady state + epilogue (drain + final-h outputs)
    step(TT - 4, 0, false, false, true,  true);    // s=2044 (last x load)
    step(TT - 3, 1, false, false, false, true);    // s=2045
    step(TT - 2, 0, false, false, false, true);    // s=2046 (stores x[2047])
    step(TT - 1, 1, false, true,  false, false);   // s=2047: l0 writes hT
    step(TT,     0, true,  true,  false, false);   // s=2048: l1 writes hT
    step(TT + 1, 1, true,  true,  false, false);   // s=2049: l2 writes hT

    // ---- fused MLP head (hfin visible after the last step's barrier) ----
    // h1 = gelu_exact(hfin @ W1^T + b1) [3,72]; out = h1 @ W2^T + b2 [3,18]
    if (tid < 4 * OO) {                   // 72 threads x 3 layers
        #pragma unroll
        for (int ml = 0; ml < NL; ++ml) {
            float a = b1[tid];
            #pragma unroll
            for (int k = 0; k < HH; ++k) a += hfin[ml][k] * W1[tid * HH + k];
            h1s[ml][tid] = 0.5f * a * (1.0f + erff(a * 0.70710678118654752f));
        }
    }
    __syncthreads();
    if (tid < NL * OO) {                  // 54 threads
        const int ol = tid / OO, o = tid % OO;
        float a = b2[o];
        #pragma unroll
        for (int m = 0; m < 4 * OO; ++m) a += h1s[ol][m] * W2[o * (4 * OO) + m];
        outp[((size_t)ol * BB + bg) * OO + o] = a;
    }
}

extern "C" void kernel_launch(void* const* d_in, const int* in_sizes, int n_in,
                              void* d_out, int out_size, void* d_ws, size_t ws_size,
                              hipStream_t stream) {
    const float* x    = (const float*)d_in[0];
    const float* Wih0 = (const float*)d_in[1];
    const float* Whh0 = (const float*)d_in[2];
    const float* bih0 = (const float*)d_in[3];
    const float* bhh0 = (const float*)d_in[4];
    const float* Wih1 = (const float*)d_in[5];
    const float* Whh1 = (const float*)d_in[6];
    const float* bih1 = (const float*)d_in[7];
    const float* bhh1 = (const float*)d_in[8];
    const float* Wih2 = (const float*)d_in[9];
    const float* Whh2 = (const float*)d_in[10];
    const float* bih2 = (const float*)d_in[11];
    const float* bhh2 = (const float*)d_in[12];
    const float* W1   = (const float*)d_in[13];
    const float* b1   = (const float*)d_in[14];
    const float* W2   = (const float*)d_in[15];
    const float* b2   = (const float*)d_in[16];

    float* out    = (float*)d_out;                 // [3,512,18] = 27648 floats
    float* hidden = out + NL * BB * OO;            // [3,512,33] = 50688 floats

    lstm_pipeline_kernel<<<BB, 128, 0, stream>>>(
        x, Wih0, Whh0, bih0, bhh0, Wih1, Whh1, bih1, bhh1,
        Wih2, Whh2, bih2, bhh2, W1, b1, W2, b2, hidden, out);
}